// Round 7
// baseline (273.209 us; speedup 1.0000x reference)
//
#include <hip/hip_runtime.h>

typedef float f32x4 __attribute__((ext_vector_type(4)));
typedef short s16x8 __attribute__((ext_vector_type(8)));
typedef short s16x4 __attribute__((ext_vector_type(4)));
typedef unsigned short u16;

#define N_COLS 4096
#define RANK 64

__device__ __forceinline__ unsigned f_asuint(float f) { union { float f; unsigned u; } v; v.f = f; return v.u; }
__device__ __forceinline__ float f_asfloat(unsigned u) { union { unsigned u; float f; } v; v.u = u; return v.f; }
// fp32 -> bf16 round-to-nearest-even
__device__ __forceinline__ short f2bf(float f) {
  unsigned u = f_asuint(f);
  return (short)((u + 0x7fffu + ((u >> 16) & 1u)) >> 16);
}

// async global->LDS, 16B per lane; LDS dest = wave-uniform base + lane*16
__device__ __forceinline__ void gload_lds16(const void* g, void* l) {
  __builtin_amdgcn_global_load_lds(
      (const __attribute__((address_space(1))) unsigned int*)g,
      (__attribute__((address_space(3))) unsigned int*)l,
      16, 0, 0);
}

// ---------------------------------------------------------------------------
// Kernel 0 (8x vectorized): W[r][n] = b_q[n/64][r] * c_q_t[r][n%64]  (bf16)
//                           a_bf[m][r] = bf16(a_q[m][r])
// ---------------------------------------------------------------------------
__global__ __launch_bounds__(256) void k_prep(const float* __restrict__ b_q,
                                              const float* __restrict__ c_q_t,
                                              const float* __restrict__ a_q,
                                              u16* __restrict__ W,
                                              u16* __restrict__ a_bf) {
  int j = blockIdx.x * 256 + threadIdx.x;   // [0, 65536)
  if (j < 32768) {
    int r = j >> 9;
    int n0 = (j << 3) & 4095;
    float b = b_q[(n0 >> 6) * RANK + r];
    const f32x4* cp = reinterpret_cast<const f32x4*>(c_q_t + (r << 6) + (n0 & 63));
    f32x4 c0 = cp[0], c1 = cp[1];
    s16x8 w;
    w[0] = f2bf(b * c0.x); w[1] = f2bf(b * c0.y); w[2] = f2bf(b * c0.z); w[3] = f2bf(b * c0.w);
    w[4] = f2bf(b * c1.x); w[5] = f2bf(b * c1.y); w[6] = f2bf(b * c1.z); w[7] = f2bf(b * c1.w);
    *reinterpret_cast<s16x8*>(W + ((size_t)j << 3)) = w;
  } else {
    int j2 = j - 32768;
    const f32x4* ap = reinterpret_cast<const f32x4*>(a_q + ((size_t)j2 << 3));
    f32x4 a0 = ap[0], a1 = ap[1];
    s16x8 v;
    v[0] = f2bf(a0.x); v[1] = f2bf(a0.y); v[2] = f2bf(a0.z); v[3] = f2bf(a0.w);
    v[4] = f2bf(a1.x); v[5] = f2bf(a1.y); v[6] = f2bf(a1.z); v[7] = f2bf(a1.w);
    *reinterpret_cast<s16x8*>(a_bf + ((size_t)j2 << 3)) = v;
  }
}

// ---------------------------------------------------------------------------
// Fused kernel: 512 blocks x 256 thr (4 waves), block owns 16 tokens.
// Phase A (= verified round-6 k_h2, K-split=1): quant(x*smooth) fused with
//   h2 = xq @ W^T over all 4096 K in 16 async double-buffered 256-col steps;
//   4-wave column-split partials reduced via LDS -> h2 bf16 in LDS.
// Phase B (= verified round-4/6 gemm2 core): out = h2 @ a_bf^T + bias over
//   16 m-chunks of 256; chunked LDS-transpose -> contiguous NT f32x4 stores.
// LDS: shmem 32K (xbuf dbuf / reduce / epilogue tile) + sml 16K + h2l 2.3K.
// ---------------------------------------------------------------------------
__global__ __launch_bounds__(256, 2) void k_fused(const float* __restrict__ x,
                                                  const float* __restrict__ smooth,
                                                  const u16* __restrict__ W,
                                                  const u16* __restrict__ a_bf,
                                                  const float* __restrict__ bias,
                                                  float* __restrict__ out) {
  const int t0 = blockIdx.x * 16;
  const int wave = threadIdx.x >> 6;   // 0..3
  const int lane = threadIdx.x & 63;
  const int quad = lane >> 4;
  const int tl = lane & 15;

  __shared__ float shmem[8192];        // 32 KB: xbuf[2][4096] / red / tile
  __shared__ float sml[4096];          // 16 KB: full smooth
  __shared__ u16 h2l[16 * 72];         // 2304 B

  float* xbuf0 = shmem;
  float* xbuf1 = shmem + 4096;

  // ---- stage smooth (linear; reads are wave-broadcast -> conflict-free) ----
#pragma unroll
  for (int rr = 0; rr < 4; ++rr)
    gload_lds16(smooth + rr * 1024 + wave * 256 + (lane << 2),
                &sml[rr * 1024 + wave * 256]);

  // ---- x stage step 0: token q*4+wave, 256-col row, 16B/lane.
  // Source col pre-swizzled (c = (lane*4) ^ ((tok&7)*4)) so LDS stays linear.
  const int colL = lane << 2;          // 0..252
#pragma unroll
  for (int q = 0; q < 4; ++q) {
    int tok = q * 4 + wave;
    int c = colL ^ ((tok & 7) << 2);
    gload_lds16(x + (size_t)(t0 + tok) * N_COLS + c, &xbuf0[tok * 256]);
  }
  __syncthreads();                     // drain smooth + step-0 stage

  f32x4 acc0 = {0.f, 0.f, 0.f, 0.f};
  f32x4 acc1 = {0.f, 0.f, 0.f, 0.f};
  f32x4 acc2 = {0.f, 0.f, 0.f, 0.f};
  f32x4 acc3 = {0.f, 0.f, 0.f, 0.f};

  const int c0w = wave * 64 + quad * 8;
  const int swz = (tl & 7) << 2;
  const u16* wpB = W + (size_t)tl * N_COLS + c0w;

#pragma unroll
  for (int t = 0; t < 16; ++t) {
    // prefetch next x tile into the other buffer (drained at this step's barrier)
    if (t + 1 < 16) {
      float* nb = ((t + 1) & 1) ? xbuf1 : xbuf0;
#pragma unroll
      for (int q = 0; q < 4; ++q) {
        int tok = q * 4 + wave;
        int c = colL ^ ((tok & 7) << 2);
        gload_lds16(x + (size_t)(t0 + tok) * N_COLS + (t + 1) * 256 + c,
                    &nb[tok * 256]);
      }
    }

    // W fragments for this step (L2-resident; latency hidden under quant VALU)
    s16x8 w8[2][4];
#pragma unroll
    for (int si = 0; si < 2; ++si)
#pragma unroll
      for (int i = 0; i < 4; ++i)
        w8[si][i] = *reinterpret_cast<const s16x8*>(
            wpB + t * 256 + si * 32 + (size_t)i * 16 * N_COLS);

    const float* xb = (t & 1) ? xbuf1 : xbuf0;
#pragma unroll
    for (int si = 0; si < 2; ++si) {
      const int cs = c0w + si * 32;
      f32x4 xa = *reinterpret_cast<const f32x4*>(xb + tl * 256 + (cs ^ swz));
      f32x4 xv = *reinterpret_cast<const f32x4*>(xb + tl * 256 + ((cs + 4) ^ swz));
      f32x4 sa = *reinterpret_cast<const f32x4*>(sml + t * 256 + cs);
      f32x4 sb = *reinterpret_cast<const f32x4*>(sml + t * 256 + cs + 4);

      float xs[8];
      xs[0] = xa.x * sa.x; xs[1] = xa.y * sa.y; xs[2] = xa.z * sa.z; xs[3] = xa.w * sa.w;
      xs[4] = xv.x * sb.x; xs[5] = xv.y * sb.y; xs[6] = xv.z * sb.z; xs[7] = xv.w * sb.w;

      // amax over the 16-block: 8 local + partner half in lane^16 (same token)
      float amax = fabsf(xs[0]);
#pragma unroll
      for (int j = 1; j < 8; ++j) amax = fmaxf(amax, fabsf(xs[j]));
      amax = fmaxf(amax, __shfl_xor(amax, 16));
      float scale = fmaxf(amax * (1.0f / 6.0f), 1e-8f);

      // searchsorted(mids, |y|, 'right') == count(|x| >= mid*scale)
      const float th0 = 0.25f * scale, th1 = 0.75f * scale, th2 = 1.25f * scale,
                  th3 = 1.75f * scale, th4 = 2.5f * scale, th5 = 3.5f * scale,
                  th6 = 5.0f * scale;
      s16x8 af;
#pragma unroll
      for (int j = 0; j < 8; ++j) {
        float ax = fabsf(xs[j]);
        float q = (ax >= th0) ? 0.5f : 0.0f;
        q = (ax >= th1) ? 1.0f : q;
        q = (ax >= th2) ? 1.5f : q;
        q = (ax >= th3) ? 2.0f : q;
        q = (ax >= th4) ? 3.0f : q;
        q = (ax >= th5) ? 4.0f : q;
        q = (ax >= th6) ? 6.0f : q;
        float xq = q * scale;
        xq = f_asfloat(f_asuint(xq) | (f_asuint(xs[j]) & 0x80000000u));
        af[j] = f2bf(xq);
      }

      acc0 = __builtin_amdgcn_mfma_f32_16x16x32_bf16(af, w8[si][0], acc0, 0, 0, 0);
      acc1 = __builtin_amdgcn_mfma_f32_16x16x32_bf16(af, w8[si][1], acc1, 0, 0, 0);
      acc2 = __builtin_amdgcn_mfma_f32_16x16x32_bf16(af, w8[si][2], acc2, 0, 0, 0);
      acc3 = __builtin_amdgcn_mfma_f32_16x16x32_bf16(af, w8[si][3], acc3, 0, 0, 0);
    }
    __syncthreads();                   // drains next-tile stage, syncs buffers
  }

  // cross-wave reduction of 4 column-split partials -> bf16 h2 in LDS.
  // red aliases xbuf0 (xbuf reads done: last step read xbuf1).
  float* red = xbuf0;
  float* rw = red + wave * 1024 + (quad * 4) * 64 + tl;
#pragma unroll
  for (int reg = 0; reg < 4; ++reg) {
    rw[reg * 64 + 0]  = acc0[reg];
    rw[reg * 64 + 16] = acc1[reg];
    rw[reg * 64 + 32] = acc2[reg];
    rw[reg * 64 + 48] = acc3[reg];
  }
  __syncthreads();
  {
    const f32x4* r4 = reinterpret_cast<const f32x4*>(red);
    f32x4 v = r4[threadIdx.x];
#pragma unroll
    for (int p = 1; p < 4; ++p) {
      f32x4 u = r4[p * 256 + threadIdx.x];
      v.x += u.x; v.y += u.y; v.z += u.z; v.w += u.w;
    }
    int t = threadIdx.x >> 4;          // token 0..15
    int rr = (threadIdx.x & 15) * 4;   // r offset
    s16x4 o4;
    o4[0] = f2bf(v.x); o4[1] = f2bf(v.y); o4[2] = f2bf(v.z); o4[3] = f2bf(v.w);
    *reinterpret_cast<s16x4*>(h2l + t * 72 + rr) = o4;
  }
  __syncthreads();

  // ---------------- Phase B: out = h2 @ a_bf^T + bias ----------------------
  // h-fragments are m-chunk-invariant: hoist.
  s16x8 h0 = *reinterpret_cast<const s16x8*>(h2l + tl * 72 + quad * 8);
  s16x8 h1 = *reinterpret_cast<const s16x8*>(h2l + tl * 72 + quad * 8 + 32);

  float* tile = shmem;                 // 16 x 260 f32 epilogue tile (16.6 KB)

  for (int mc = 0; mc < 16; ++mc) {
    const int m0 = mc * 256;
    f32x4 acc[4] = {{0.f,0.f,0.f,0.f},{0.f,0.f,0.f,0.f},{0.f,0.f,0.f,0.f},{0.f,0.f,0.f,0.f}};
#pragma unroll
    for (int mg = 0; mg < 4; ++mg) {
      const u16* ap = a_bf + (size_t)(m0 + wave * 64 + mg * 16 + tl) * RANK + quad * 8;
      s16x8 b0 = *reinterpret_cast<const s16x8*>(ap);
      s16x8 b1 = *reinterpret_cast<const s16x8*>(ap + 32);
      acc[mg] = __builtin_amdgcn_mfma_f32_16x16x32_bf16(h0, b0, acc[mg], 0, 0, 0);
      acc[mg] = __builtin_amdgcn_mfma_f32_16x16x32_bf16(h1, b1, acc[mg], 0, 0, 0);
    }

    __syncthreads();                   // protect tile from previous chunk's reads
#pragma unroll
    for (int mg = 0; mg < 4; ++mg)
#pragma unroll
      for (int reg = 0; reg < 4; ++reg)
        tile[(quad * 4 + reg) * 260 + wave * 64 + mg * 16 + tl] = acc[mg][reg];
    __syncthreads();

#pragma unroll
    for (int i = 0; i < 4; ++i) {
      int idx = threadIdx.x + i * 256;   // 1024 float4 = 16 x 256 chunk
      int row = idx >> 6;
      int c4 = (idx & 63) << 2;
      f32x4 v = *reinterpret_cast<const f32x4*>(tile + row * 260 + c4);
      f32x4 b = *reinterpret_cast<const f32x4*>(bias + m0 + c4);
      f32x4 ov;
      ov.x = v.x + b.x; ov.y = v.y + b.y; ov.z = v.z + b.z; ov.w = v.w + b.w;
      __builtin_nontemporal_store(ov,
        reinterpret_cast<f32x4*>(out + (size_t)(t0 + row) * N_COLS + m0 + c4));
    }
  }
}

// ---------------------------------------------------------------------------
extern "C" void kernel_launch(void* const* d_in, const int* in_sizes, int n_in,
                              void* d_out, int out_size, void* d_ws, size_t ws_size,
                              hipStream_t stream) {
  const float* x      = (const float*)d_in[0];
  const float* smooth = (const float*)d_in[1];
  const float* a_q    = (const float*)d_in[2];
  const float* b_q    = (const float*)d_in[3];
  const float* c_q_t  = (const float*)d_in[4];
  const float* bias   = (const float*)d_in[5];
  float* out = (float*)d_out;

  const int T = in_sizes[0] / N_COLS;  // 8192 tokens

  u16* W    = (u16*)d_ws;                                   // 512 KB
  u16* a_bf = (u16*)((char*)d_ws + 524288);                 // 512 KB

  k_prep<<<256, 256, 0, stream>>>(b_q, c_q_t, a_q, W, a_bf);
  k_fused<<<T / 16, 256, 0, stream>>>(x, smooth, W, a_bf, bias, out);
}